// Round 6
// baseline (1591.398 us; speedup 1.0000x reference)
//
#include <hip/hip_runtime.h>
#include <math.h>

#define H 512
#define V 32000
#define NVB 250     // vocab blocks (32000 / 128)

typedef unsigned short ushort_t;
typedef __attribute__((ext_vector_type(8))) short short8;
typedef __attribute__((ext_vector_type(4))) float f32x4;

// ---- bf16 split helpers (bit-level RNE) ----
__device__ __forceinline__ unsigned short f2bf(float x) {
    unsigned int u; __builtin_memcpy(&u, &x, 4);
    unsigned int r = (u + 0x7fffu + ((u >> 16) & 1u)) >> 16;
    return (unsigned short)r;
}
__device__ __forceinline__ float bfu2f(unsigned short h) {
    unsigned int u = ((unsigned int)h) << 16;
    float f; __builtin_memcpy(&f, &u, 4);
    return f;
}

__device__ __forceinline__ void t2_insert(float& m1, int& c1, float& m2, int& c2,
                                          float v, int idx) {
    if (v > m1 || (v == m1 && idx < c1)) { m2 = m1; c2 = c1; m1 = v; c1 = idx; }
    else if (v > m2 || (v == m2 && idx < c2)) { m2 = v; c2 = idx; }
}

// ---------------------------------------------------------------------------
// Kernel 1: ts = tanh(A @ W_em + b_em)
// ---------------------------------------------------------------------------
__global__ __launch_bounds__(256) void k_emstate(
    const float* __restrict__ y_hidden, const float* __restrict__ y_null,
    const float* __restrict__ W, const float* __restrict__ bias,
    float* __restrict__ ts)
{
    const int NR = 2049;
    __shared__ float As[16][64];
    __shared__ float Bs[16][64];
    int rb = blockIdx.y, cb = blockIdx.x;
    int row0 = rb * 64, col0 = cb * 64;
    int tid = threadIdx.x;
    int tr = tid >> 4, tc = tid & 15;
    float acc[4][4] = {};
    for (int k0 = 0; k0 < H; k0 += 16) {
        {
            int r = tid >> 2;
            int kk = (tid & 3) << 2;
            int row = row0 + r;
            float4 v = make_float4(0.f, 0.f, 0.f, 0.f);
            if (row < 2048)       v = *(const float4*)&y_hidden[row * H + k0 + kk];
            else if (row == 2048) v = *(const float4*)&y_null[k0 + kk];
            As[kk + 0][r] = v.x; As[kk + 1][r] = v.y;
            As[kk + 2][r] = v.z; As[kk + 3][r] = v.w;
            int bk = tid >> 4, bc = (tid & 15) << 2;
            *(float4*)&Bs[bk][bc] = *(const float4*)&W[(k0 + bk) * H + col0 + bc];
        }
        __syncthreads();
#pragma unroll
        for (int kk = 0; kk < 16; ++kk) {
            float4 a = *(float4*)&As[kk][tr * 4];
            float4 b = *(float4*)&Bs[kk][tc * 4];
            float av[4] = {a.x, a.y, a.z, a.w};
            float bv[4] = {b.x, b.y, b.z, b.w};
#pragma unroll
            for (int i = 0; i < 4; i++)
#pragma unroll
                for (int j = 0; j < 4; j++) acc[i][j] += av[i] * bv[j];
        }
        __syncthreads();
    }
#pragma unroll
    for (int i = 0; i < 4; i++) {
        int row = row0 + tr * 4 + i;
        if (row >= NR) break;
#pragma unroll
        for (int j = 0; j < 4; j++) {
            int col = col0 + tc * 4 + j;
            ts[(size_t)row * H + col] = tanhf(acc[i][j] + bias[col]);
        }
    }
}

// ---------------------------------------------------------------------------
// Pack A (f32 [rows][512]) -> fragment-block bf16 hi/lo.
// Block (n16,k32) = 1 KB at offset (n16*16+k32)*512 ushorts; lane l holds
// elems (m=n16*16+(l&15), k=k32*32+(l>>4)*8 .. +7), 16 B contiguous.
// ---------------------------------------------------------------------------
__global__ __launch_bounds__(256) void k_packA(
    const float* __restrict__ A, int nvalid, int nb16,
    ushort_t* __restrict__ Ph, ushort_t* __restrict__ Pl)
{
    int c = blockIdx.x * 256 + threadIdx.x;
    if (c >= nb16 * 1024) return;
    int n16 = c >> 10, rem = c & 1023, k32 = rem >> 6, l = rem & 63;
    int m = n16 * 16 + (l & 15);
    int k = k32 * 32 + (l >> 4) * 8;
    float v[8];
    if (m < nvalid) {
        *(float4*)&v[0] = *(const float4*)&A[(size_t)m * H + k];
        *(float4*)&v[4] = *(const float4*)&A[(size_t)m * H + k + 4];
    } else {
#pragma unroll
        for (int j = 0; j < 8; ++j) v[j] = 0.f;
    }
    unsigned int hh[4], lo[4];
#pragma unroll
    for (int p = 0; p < 4; ++p) {
        unsigned short h0 = f2bf(v[2 * p]), h1 = f2bf(v[2 * p + 1]);
        hh[p] = (unsigned int)h0 | ((unsigned int)h1 << 16);
        unsigned short l0 = f2bf(v[2 * p] - bfu2f(h0));
        unsigned short l1 = f2bf(v[2 * p + 1] - bfu2f(h1));
        lo[p] = (unsigned int)l0 | ((unsigned int)l1 << 16);
    }
    size_t o = ((size_t)n16 * 16 + k32) * 512 + l * 8;
    *(uint4*)&Ph[o] = make_uint4(hh[0], hh[1], hh[2], hh[3]);
    *(uint4*)&Pl[o] = make_uint4(lo[0], lo[1], lo[2], lo[3]);
}

// ---------------------------------------------------------------------------
// Pack W (f32 [512][32000], k-major) -> fragment-block bf16 hi/lo (n as m).
// ---------------------------------------------------------------------------
__global__ __launch_bounds__(256) void k_packW(
    const float* __restrict__ W,
    ushort_t* __restrict__ Ph, ushort_t* __restrict__ Pl)
{
    int c = blockIdx.x * 256 + threadIdx.x;
    int n16 = c >> 10, rem = c & 1023, k32 = rem >> 6, l = rem & 63;
    int n = n16 * 16 + (l & 15);
    int k = k32 * 32 + (l >> 4) * 8;
    float v[8];
#pragma unroll
    for (int j = 0; j < 8; ++j) v[j] = W[(size_t)(k + j) * V + n];
    unsigned int hh[4], lo[4];
#pragma unroll
    for (int p = 0; p < 4; ++p) {
        unsigned short h0 = f2bf(v[2 * p]), h1 = f2bf(v[2 * p + 1]);
        hh[p] = (unsigned int)h0 | ((unsigned int)h1 << 16);
        unsigned short l0 = f2bf(v[2 * p] - bfu2f(h0));
        unsigned short l1 = f2bf(v[2 * p + 1] - bfu2f(h1));
        lo[p] = (unsigned int)l0 | ((unsigned int)l1 << 16);
    }
    size_t o = ((size_t)n16 * 16 + k32) * 512 + l * 8;
    *(uint4*)&Ph[o] = make_uint4(hh[0], hh[1], hh[2], hh[3]);
    *(uint4*)&Pl[o] = make_uint4(lo[0], lo[1], lo[2], lo[3]);
}

// ---------------------------------------------------------------------------
// Kernel 2: split-bf16 MFMA GEMM, register-direct (no LDS, no barriers).
// Tile 128x128, BK=32, 4 waves (2x2, each 64x64). Fragments loaded straight
// from packed global layout into registers; double-buffered prefetch.
// acc = Ah*Bh + Ah*Bl + Al*Bh via mfma_f32_16x16x32_bf16.
// Grid: (rb, vb) — row-blocks fastest for B-tile L2 locality per XCD.
// ---------------------------------------------------------------------------
template<bool TOP2>
__global__ __launch_bounds__(256) void k_gemm(
    const ushort_t* __restrict__ Ah, const ushort_t* __restrict__ Al,
    const ushort_t* __restrict__ Bh, const ushort_t* __restrict__ Bl,
    const float* __restrict__ bias,
    float* __restrict__ pL,
    float* __restrict__ pM1, float* __restrict__ pM2,
    int* __restrict__ pI1, int* __restrict__ pI2)
{
    __shared__ float sc_s[128][2];
    __shared__ float sc_m1[128][2], sc_m2[128][2];
    __shared__ int   sc_c1[128][2], sc_c2[128][2];

    const int tid = threadIdx.x;
    const int rb = blockIdx.x, vb = blockIdx.y;
    const int row0 = rb * 128, col0 = vb * 128;
    const int lane = tid & 63, w = tid >> 6;
    const int wy = w >> 1, wx = w & 1;     // wave grid 2x2, each wave 64x64

    f32x4 acc[4][4];
#pragma unroll
    for (int i = 0; i < 4; ++i)
#pragma unroll
        for (int j = 0; j < 4; ++j)
#pragma unroll
            for (int r = 0; r < 4; ++r) acc[i][j][r] = 0.f;

    // fragment base pointers (lane offset included); block (n16,k32) at
    // (n16*16+k32)*512 ushorts; per i-step n16+1 -> +8192 ushorts; per k32 -> +512.
    const int nA = (row0 >> 4) + wy * 4;   // first A 16-row block for this wave
    const int nB = (col0 >> 4) + wx * 4;   // first B 16-col block
    const ushort_t* aH = Ah + (size_t)nA * 8192 + lane * 8;
    const ushort_t* aL = Al + (size_t)nA * 8192 + lane * 8;
    const ushort_t* bH = Bh + (size_t)nB * 8192 + lane * 8;
    const ushort_t* bL = Bl + (size_t)nB * 8192 + lane * 8;

    short8 a0h[4], a0l[4], b0h[4], b0l[4];
    short8 a1h[4], a1l[4], b1h[4], b1l[4];

#define LOAD_ITER(AH, AL, BH, BL, it)                                   \
    {                                                                   \
        const size_t ko = (size_t)(it) * 512;                           \
        _Pragma("unroll")                                               \
        for (int i = 0; i < 4; ++i) {                                   \
            AH[i] = *(const short8*)(aH + (size_t)i * 8192 + ko);       \
            AL[i] = *(const short8*)(aL + (size_t)i * 8192 + ko);       \
            BH[i] = *(const short8*)(bH + (size_t)i * 8192 + ko);       \
            BL[i] = *(const short8*)(bL + (size_t)i * 8192 + ko);       \
        }                                                               \
    }

#define COMP_ITER(AH, AL, BH, BL)                                       \
    {                                                                   \
        _Pragma("unroll")                                               \
        for (int i = 0; i < 4; ++i)                                     \
            _Pragma("unroll")                                           \
            for (int j = 0; j < 4; ++j) {                               \
                acc[i][j] = __builtin_amdgcn_mfma_f32_16x16x32_bf16(    \
                    AH[i], BH[j], acc[i][j], 0, 0, 0);                  \
                acc[i][j] = __builtin_amdgcn_mfma_f32_16x16x32_bf16(    \
                    AH[i], BL[j], acc[i][j], 0, 0, 0);                  \
                acc[i][j] = __builtin_amdgcn_mfma_f32_16x16x32_bf16(    \
                    AL[i], BH[j], acc[i][j], 0, 0, 0);                  \
            }                                                           \
    }

    LOAD_ITER(a0h, a0l, b0h, b0l, 0)
#pragma unroll
    for (int it = 0; it < 16; it += 2) {
        if (it + 1 < 16) LOAD_ITER(a1h, a1l, b1h, b1l, it + 1)
        COMP_ITER(a0h, a0l, b0h, b0l)
        if (it + 2 < 16) LOAD_ITER(a0h, a0l, b0h, b0l, it + 2)
        if (it + 1 < 16) COMP_ITER(a1h, a1l, b1h, b1l)
    }
#undef LOAD_ITER
#undef COMP_ITER

    // ---- epilogue: shift-free sumexp (+ top-2) per row over 128 cols ----
    // C/D layout (16x16x32): col = lane&15, row = (lane>>4)*4 + reg.
    float b4[4];
#pragma unroll
    for (int j = 0; j < 4; ++j) b4[j] = bias[col0 + wx * 64 + j * 16 + (lane & 15)];
    const int colbase = col0 + wx * 64 + (lane & 15);

#pragma unroll
    for (int i = 0; i < 4; ++i) {
#pragma unroll
        for (int r = 0; r < 4; ++r) {
            float s = 0.f;
            float m1 = -3e38f, m2 = -3e38f; int c1 = 0x7fffffff, c2 = 0x7fffffff;
#pragma unroll
            for (int j = 0; j < 4; ++j) {
                float v = acc[i][j][r] + b4[j];
                s += __expf(v);
                if (TOP2) t2_insert(m1, c1, m2, c2, v, colbase + j * 16);
            }
            for (int st = 1; st < 16; st <<= 1) {
                s += __shfl_xor(s, st, 64);
                if (TOP2) {
                    float om1 = __shfl_xor(m1, st, 64); int oc1 = __shfl_xor(c1, st, 64);
                    float om2 = __shfl_xor(m2, st, 64); int oc2 = __shfl_xor(c2, st, 64);
                    t2_insert(m1, c1, m2, c2, om1, oc1);
                    t2_insert(m1, c1, m2, c2, om2, oc2);
                }
            }
            if ((lane & 15) == 0) {
                int rowLoc = wy * 64 + i * 16 + (lane >> 4) * 4 + r;
                sc_s[rowLoc][wx] = s;
                if (TOP2) {
                    sc_m1[rowLoc][wx] = m1; sc_c1[rowLoc][wx] = c1;
                    sc_m2[rowLoc][wx] = m2; sc_c2[rowLoc][wx] = c2;
                }
            }
        }
    }
    __syncthreads();
    if (tid < 128) {
        int rowG = row0 + tid;
        pL[(size_t)rowG * NVB + vb] = sc_s[tid][0] + sc_s[tid][1];
        if (TOP2) {
            float m1 = sc_m1[tid][0]; int c1 = sc_c1[tid][0];
            float m2 = sc_m2[tid][0]; int c2 = sc_c2[tid][0];
            t2_insert(m1, c1, m2, c2, sc_m1[tid][1], sc_c1[tid][1]);
            t2_insert(m1, c1, m2, c2, sc_m2[tid][1], sc_c2[tid][1]);
            pM1[(size_t)rowG * NVB + vb] = m1;
            pM2[(size_t)rowG * NVB + vb] = m2;
            pI1[(size_t)rowG * NVB + vb] = c1;
            pI2[(size_t)rowG * NVB + vb] = c2;
        }
    }
}

// ---------------------------------------------------------------------------
// Kernel 3a: combine source partials -> L (denominator only)
// ---------------------------------------------------------------------------
__global__ __launch_bounds__(256) void k_combine_src(
    const float* __restrict__ pL, int nrows, float* __restrict__ L)
{
    int w = threadIdx.x >> 6, ll = threadIdx.x & 63;
    int row = blockIdx.x * 4 + w;
    if (row >= nrows) return;
    const float* p = &pL[(size_t)row * NVB];
    float s = 0.f;
    for (int vb = ll; vb < NVB; vb += 64) s += p[vb];
    for (int st = 1; st < 64; st <<= 1) s += __shfl_xor(s, st, 64);
    if (ll == 0) L[row] = s;
}

// ---------------------------------------------------------------------------
// Kernel 3b: combine target partials -> L + global approx top-2 candidates
// ---------------------------------------------------------------------------
__global__ __launch_bounds__(256) void k_combine_tgt(
    const float* __restrict__ pL,
    const float* __restrict__ pM1, const float* __restrict__ pM2,
    const int* __restrict__ pI1, const int* __restrict__ pI2,
    float* __restrict__ L, int* __restrict__ C0, int* __restrict__ C1)
{
    int w = threadIdx.x >> 6, ll = threadIdx.x & 63;
    int row = blockIdx.x * 4 + w;
    if (row >= 2048) return;
    size_t base = (size_t)row * NVB;
    float s = 0.f;
    float m1 = -3e38f, m2 = -3e38f; int c1 = 0x7fffffff, c2 = 0x7fffffff;
    for (int vb = ll; vb < NVB; vb += 64) {
        s += pL[base + vb];
        t2_insert(m1, c1, m2, c2, pM1[base + vb], pI1[base + vb]);
        t2_insert(m1, c1, m2, c2, pM2[base + vb], pI2[base + vb]);
    }
    for (int st = 1; st < 64; st <<= 1) {
        s += __shfl_xor(s, st, 64);
        float om1 = __shfl_xor(m1, st, 64); int oc1 = __shfl_xor(c1, st, 64);
        float om2 = __shfl_xor(m2, st, 64); int oc2 = __shfl_xor(c2, st, 64);
        t2_insert(m1, c1, m2, c2, om1, oc1);
        t2_insert(m1, c1, m2, c2, om2, oc2);
    }
    if (ll == 0) { L[row] = s; C0[row] = c1; C1[row] = c2; }
}

// ---------------------------------------------------------------------------
// Kernel 4: emission output (exact f32 dot for gathered columns)
// ---------------------------------------------------------------------------
__global__ __launch_bounds__(256) void k_emission(
    const float* __restrict__ ts, const float* __restrict__ W_sv,
    const float* __restrict__ b_sv, const int* __restrict__ sources,
    const float* __restrict__ L, float* __restrict__ out)
{
    __shared__ float wcol[H];
    __shared__ float sbias;
    int b = blockIdx.y, tx = blockIdx.x;
    int tid = threadIdx.x;
    int s = sources[b * 64 + tx];
    wcol[tid]       = W_sv[(size_t)tid * V + s];
    wcol[tid + 256] = W_sv[(size_t)(tid + 256) * V + s];
    if (tid == 0) sbias = b_sv[s];
    __syncthreads();
    int w = tid >> 6, ll = tid & 63;
    for (int r = w; r <= 64; r += 4) {
        int row = (r < 64) ? (b * 64 + r) : 2048;
        const float* a = &ts[(size_t)row * H];
        float sum = 0.f;
#pragma unroll
        for (int j = 0; j < 8; ++j) sum += a[ll * 8 + j] * wcol[ll * 8 + j];
        for (int m2 = 1; m2 < 64; m2 <<= 1) sum += __shfl_xor(sum, m2, 64);
        float prob = __expf(sum + sbias) / L[row];
        if (r < 64) {
            if (ll == 0) out[b * 8192 + r * 64 + tx] = prob;
        } else {
            out[b * 8192 + (64 + ll) * 64 + tx] = prob;
        }
    }
}

// ---------------------------------------------------------------------------
// Kernel 5: target epilogue — exact recompute of token + 2 argmax candidates
// ---------------------------------------------------------------------------
__global__ __launch_bounds__(256) void k_target_final(
    const float* __restrict__ tstate,
    const float* __restrict__ W_tv, const float* __restrict__ b_tv,
    const int* __restrict__ targets, const int* __restrict__ tlen,
    const float* __restrict__ L, const int* __restrict__ C0,
    const int* __restrict__ C1,
    float* __restrict__ out_exp, float* __restrict__ out_log,
    float* __restrict__ out_pred)
{
    int w = threadIdx.x >> 6, ll = threadIdx.x & 63;
    int row = blockIdx.x * 4 + w;
    if (row >= 2048) return;
    int tok = targets[row], a0 = C0[row], a1 = C1[row];
    const float* a = &tstate[(size_t)row * H];
    float s0 = 0.f, s1 = 0.f, s2 = 0.f;
#pragma unroll
    for (int j = 0; j < 8; ++j) {
        int k = ll * 8 + j;
        float av = a[k];
        const float* wr = &W_tv[(size_t)k * V];
        s0 += av * wr[tok]; s1 += av * wr[a0]; s2 += av * wr[a1];
    }
    for (int st = 1; st < 64; st <<= 1) {
        s0 += __shfl_xor(s0, st, 64);
        s1 += __shfl_xor(s1, st, 64);
        s2 += __shfl_xor(s2, st, 64);
    }
    if (ll == 0) {
        float ltok = s0 + b_tv[tok];
        float v0 = s1 + b_tv[a0], v1 = s2 + b_tv[a1];
        int pred = (v1 > v0 || (v1 == v0 && a1 < a0)) ? a1 : a0;
        float Li = L[row];
        int bb = row >> 6, t = row & 63;
        int mask = (t < tlen[bb]) ? 1 : 0;
        float prob = __expf(ltok) / Li;
        out_exp[row]  = mask ? prob : 0.f;
        out_log[row]  = mask ? (ltok - __logf(Li)) : 0.f;
        out_pred[row] = (float)pred;
    }
}

// ---------------------------------------------------------------------------
extern "C" void kernel_launch(void* const* d_in, const int* in_sizes, int n_in,
                              void* d_out, int out_size, void* d_ws, size_t ws_size,
                              hipStream_t stream)
{
    const float* y_hidden = (const float*)d_in[0];
    const float* y_null   = (const float*)d_in[1];
    const float* tstate   = (const float*)d_in[2];
    const float* W_em     = (const float*)d_in[3];
    const float* b_em     = (const float*)d_in[4];
    const float* W_sv     = (const float*)d_in[5];
    const float* b_sv     = (const float*)d_in[6];
    const float* W_tv     = (const float*)d_in[7];
    const float* b_tv     = (const float*)d_in[8];
    const int*   sources  = (const int*)d_in[9];
    const int*   targets  = (const int*)d_in[10];
    const int*   tlen     = (const int*)d_in[11];

    float* out = (float*)d_out;
    float* out_em   = out;
    float* out_exp  = out + 262144;
    float* out_log  = out + 264192;
    float* out_pred = out + 266240;

    // ---- workspace layout (float units) ----
    float* ws = (float*)d_ws;
    size_t off = 0;
    float*    ts    = ws + off; off += (size_t)2176 * H;
    ushort_t* tsPh  = (ushort_t*)(ws + off); off += (size_t)2176 * H / 2;
    ushort_t* tsPl  = (ushort_t*)(ws + off); off += (size_t)2176 * H / 2;
    ushort_t* ttPh  = (ushort_t*)(ws + off); off += (size_t)2048 * H / 2;
    ushort_t* ttPl  = (ushort_t*)(ws + off); off += (size_t)2048 * H / 2;
    ushort_t* Wh    = (ushort_t*)(ws + off); off += (size_t)V * H / 2;   // reused
    ushort_t* Wl    = (ushort_t*)(ws + off); off += (size_t)V * H / 2;
    float* pL0  = ws + off; off += (size_t)2176 * NVB;
    float* pL1  = ws + off; off += (size_t)2048 * NVB;
    float* pM1a = ws + off; off += (size_t)2048 * NVB;
    float* pM1b = ws + off; off += (size_t)2048 * NVB;
    int*   pI1a = (int*)(ws + off); off += (size_t)2048 * NVB;
    int*   pI1b = (int*)(ws + off); off += (size_t)2048 * NVB;
    float* L0   = ws + off; off += 2176;
    float* L1   = ws + off; off += 2048;
    int*   C0   = (int*)(ws + off); off += 2048;
    int*   C1   = (int*)(ws + off); off += 2048;

    // 1) hidden-state transform
    k_emstate<<<dim3(8, 33), 256, 0, stream>>>(y_hidden, y_null, W_em, b_em, ts);

    // 1b) pack A-side operands into fragment-block bf16 hi/lo
    k_packA<<<(136 * 1024) / 256, 256, 0, stream>>>(ts, 2049, 136, tsPh, tsPl);
    k_packA<<<(128 * 1024) / 256, 256, 0, stream>>>(tstate, 2048, 128, ttPh, ttPl);

    // 2a) source side: pack W_sv, GEMM (grid: rb fastest for B L2 locality)
    k_packW<<<(2000 * 1024) / 256, 256, 0, stream>>>(W_sv, Wh, Wl);
    k_gemm<false><<<dim3(17, NVB), 256, 0, stream>>>(
        tsPh, tsPl, Wh, Wl, b_sv, pL0, nullptr, nullptr, nullptr, nullptr);

    // 2b) target side: pack W_tv (buffer reuse, stream-ordered), GEMM
    k_packW<<<(2000 * 1024) / 256, 256, 0, stream>>>(W_tv, Wh, Wl);
    k_gemm<true><<<dim3(16, NVB), 256, 0, stream>>>(
        ttPh, ttPl, Wh, Wl, b_tv, pL1, pM1a, pM1b, pI1a, pI1b);

    // 3) combine partials
    k_combine_src<<<(2049 + 3) / 4, 256, 0, stream>>>(pL0, 2049, L0);
    k_combine_tgt<<<2048 / 4, 256, 0, stream>>>(pL1, pM1a, pM1b, pI1a, pI1b,
                                                L1, C0, C1);

    // 4) emission gather (exact f32 logits)
    k_emission<<<dim3(64, 32), 256, 0, stream>>>(ts, W_sv, b_sv, sources, L0, out_em);

    // 5) target epilogue with exact candidate recompute
    k_target_final<<<2048 / 4, 256, 0, stream>>>(tstate, W_tv, b_tv, targets, tlen,
                                                 L1, C0, C1,
                                                 out_exp, out_log, out_pred);
}

// Round 7
// 1374.602 us; speedup vs baseline: 1.1577x; 1.1577x over previous
//
#include <hip/hip_runtime.h>
#include <math.h>

#define H 512
#define V 32000
#define NVB 250     // vocab blocks (32000 / 128)

typedef unsigned short ushort_t;
typedef __attribute__((ext_vector_type(8))) short short8;
typedef __attribute__((ext_vector_type(4))) float f32x4;

// ---- bf16 split helpers (bit-level RNE) ----
__device__ __forceinline__ unsigned short f2bf(float x) {
    unsigned int u; __builtin_memcpy(&u, &x, 4);
    unsigned int r = (u + 0x7fffu + ((u >> 16) & 1u)) >> 16;
    return (unsigned short)r;
}
__device__ __forceinline__ float bfu2f(unsigned short h) {
    unsigned int u = ((unsigned int)h) << 16;
    float f; __builtin_memcpy(&f, &u, 4);
    return f;
}

__device__ __forceinline__ void t2_insert(float& m1, int& c1, float& m2, int& c2,
                                          float v, int idx) {
    if (v > m1 || (v == m1 && idx < c1)) { m2 = m1; c2 = c1; m1 = v; c1 = idx; }
    else if (v > m2 || (v == m2 && idx < c2)) { m2 = v; c2 = idx; }
}

// async global->LDS, 16 bytes/lane; LDS dest = wave-uniform base + lane*16
__device__ __forceinline__ void gl16(const void* g, void* l) {
    __builtin_amdgcn_global_load_lds(
        (const __attribute__((address_space(1))) void*)g,
        (__attribute__((address_space(3))) void*)l,
        16, 0, 0);
}

// ---------------------------------------------------------------------------
// Kernel 1: ts = tanh(A @ W_em + b_em)
// ---------------------------------------------------------------------------
__global__ __launch_bounds__(256) void k_emstate(
    const float* __restrict__ y_hidden, const float* __restrict__ y_null,
    const float* __restrict__ W, const float* __restrict__ bias,
    float* __restrict__ ts)
{
    const int NR = 2049;
    __shared__ float As[16][64];
    __shared__ float Bs[16][64];
    int rb = blockIdx.y, cb = blockIdx.x;
    int row0 = rb * 64, col0 = cb * 64;
    int tid = threadIdx.x;
    int tr = tid >> 4, tc = tid & 15;
    float acc[4][4] = {};
    for (int k0 = 0; k0 < H; k0 += 16) {
        {
            int r = tid >> 2;
            int kk = (tid & 3) << 2;
            int row = row0 + r;
            float4 v = make_float4(0.f, 0.f, 0.f, 0.f);
            if (row < 2048)       v = *(const float4*)&y_hidden[row * H + k0 + kk];
            else if (row == 2048) v = *(const float4*)&y_null[k0 + kk];
            As[kk + 0][r] = v.x; As[kk + 1][r] = v.y;
            As[kk + 2][r] = v.z; As[kk + 3][r] = v.w;
            int bk = tid >> 4, bc = (tid & 15) << 2;
            *(float4*)&Bs[bk][bc] = *(const float4*)&W[(k0 + bk) * H + col0 + bc];
        }
        __syncthreads();
#pragma unroll
        for (int kk = 0; kk < 16; ++kk) {
            float4 a = *(float4*)&As[kk][tr * 4];
            float4 b = *(float4*)&Bs[kk][tc * 4];
            float av[4] = {a.x, a.y, a.z, a.w};
            float bv[4] = {b.x, b.y, b.z, b.w};
#pragma unroll
            for (int i = 0; i < 4; i++)
#pragma unroll
                for (int j = 0; j < 4; j++) acc[i][j] += av[i] * bv[j];
        }
        __syncthreads();
    }
#pragma unroll
    for (int i = 0; i < 4; i++) {
        int row = row0 + tr * 4 + i;
        if (row >= NR) break;
#pragma unroll
        for (int j = 0; j < 4; j++) {
            int col = col0 + tc * 4 + j;
            ts[(size_t)row * H + col] = tanhf(acc[i][j] + bias[col]);
        }
    }
}

// ---------------------------------------------------------------------------
// Pack A (f32 [rows][512]) -> fragment-block bf16 hi/lo.
// Block (n16,k32) = 1 KB at offset (n16*16+k32)*512 ushorts; lane l holds
// elems (m=n16*16+(l&15), k=k32*32+(l>>4)*8 .. +7), 16 B contiguous.
// ---------------------------------------------------------------------------
__global__ __launch_bounds__(256) void k_packA(
    const float* __restrict__ A, int nvalid, int nb16,
    ushort_t* __restrict__ Ph, ushort_t* __restrict__ Pl)
{
    int c = blockIdx.x * 256 + threadIdx.x;
    if (c >= nb16 * 1024) return;
    int n16 = c >> 10, rem = c & 1023, k32 = rem >> 6, l = rem & 63;
    int m = n16 * 16 + (l & 15);
    int k = k32 * 32 + (l >> 4) * 8;
    float v[8];
    if (m < nvalid) {
        *(float4*)&v[0] = *(const float4*)&A[(size_t)m * H + k];
        *(float4*)&v[4] = *(const float4*)&A[(size_t)m * H + k + 4];
    } else {
#pragma unroll
        for (int j = 0; j < 8; ++j) v[j] = 0.f;
    }
    unsigned int hh[4], lo[4];
#pragma unroll
    for (int p = 0; p < 4; ++p) {
        unsigned short h0 = f2bf(v[2 * p]), h1 = f2bf(v[2 * p + 1]);
        hh[p] = (unsigned int)h0 | ((unsigned int)h1 << 16);
        unsigned short l0 = f2bf(v[2 * p] - bfu2f(h0));
        unsigned short l1 = f2bf(v[2 * p + 1] - bfu2f(h1));
        lo[p] = (unsigned int)l0 | ((unsigned int)l1 << 16);
    }
    size_t o = ((size_t)n16 * 16 + k32) * 512 + l * 8;
    *(uint4*)&Ph[o] = make_uint4(hh[0], hh[1], hh[2], hh[3]);
    *(uint4*)&Pl[o] = make_uint4(lo[0], lo[1], lo[2], lo[3]);
}

// ---------------------------------------------------------------------------
// Pack W (f32 [512][32000], k-major) -> fragment-block bf16 hi/lo (n as m).
// ---------------------------------------------------------------------------
__global__ __launch_bounds__(256) void k_packW(
    const float* __restrict__ W,
    ushort_t* __restrict__ Ph, ushort_t* __restrict__ Pl)
{
    int c = blockIdx.x * 256 + threadIdx.x;
    int n16 = c >> 10, rem = c & 1023, k32 = rem >> 6, l = rem & 63;
    int n = n16 * 16 + (l & 15);
    int k = k32 * 32 + (l >> 4) * 8;
    float v[8];
#pragma unroll
    for (int j = 0; j < 8; ++j) v[j] = W[(size_t)(k + j) * V + n];
    unsigned int hh[4], lo[4];
#pragma unroll
    for (int p = 0; p < 4; ++p) {
        unsigned short h0 = f2bf(v[2 * p]), h1 = f2bf(v[2 * p + 1]);
        hh[p] = (unsigned int)h0 | ((unsigned int)h1 << 16);
        unsigned short l0 = f2bf(v[2 * p] - bfu2f(h0));
        unsigned short l1 = f2bf(v[2 * p + 1] - bfu2f(h1));
        lo[p] = (unsigned int)l0 | ((unsigned int)l1 << 16);
    }
    size_t o = ((size_t)n16 * 16 + k32) * 512 + l * 8;
    *(uint4*)&Ph[o] = make_uint4(hh[0], hh[1], hh[2], hh[3]);
    *(uint4*)&Pl[o] = make_uint4(lo[0], lo[1], lo[2], lo[3]);
}

// ---------------------------------------------------------------------------
// Kernel 2: split-bf16 MFMA GEMM, ASYNC double-buffered LDS pipeline.
// Tile 128x128, BK=32, 4 waves (2x2, each 64x64), mfma_f32_16x16x32_bf16.
// Per iter (one raw s_barrier): wait vmcnt(0) [prev issue landed] -> barrier
// -> issue 8 gl16 into NEXT buffer (flies under this iter's MFMAs)
// -> ds_read this buffer -> 48 MFMAs. No __syncthreads in the K-loop, so no
// compiler-forced vmcnt(0) drain between issue and compute.
// ---------------------------------------------------------------------------
template<bool TOP2>
__global__ __launch_bounds__(256) void k_gemm(
    const ushort_t* __restrict__ Ah, const ushort_t* __restrict__ Al,
    const ushort_t* __restrict__ Bh, const ushort_t* __restrict__ Bl,
    const float* __restrict__ bias,
    float* __restrict__ pL,
    float* __restrict__ pM1, float* __restrict__ pM2,
    int* __restrict__ pI1, int* __restrict__ pI2)
{
    // 2 buffers x 4 arrays x 8 KB = 64 KB
    __shared__ __attribute__((aligned(16))) ushort_t AshB[2][8 * 512];
    __shared__ __attribute__((aligned(16))) ushort_t AslB[2][8 * 512];
    __shared__ __attribute__((aligned(16))) ushort_t BshB[2][8 * 512];
    __shared__ __attribute__((aligned(16))) ushort_t BslB[2][8 * 512];
    __shared__ float sc_s[128][2];
    __shared__ float sc_m1[128][2], sc_m2[128][2];
    __shared__ int   sc_c1[128][2], sc_c2[128][2];

    const int tid = threadIdx.x;
    const int rb = blockIdx.x, vb = blockIdx.y;
    const int row0 = rb * 128, col0 = vb * 128;
    const int lane = tid & 63, w = tid >> 6;
    const int wy = w >> 1, wx = w & 1;     // wave grid 2x2, each wave 64x64

    f32x4 acc[4][4];
#pragma unroll
    for (int i = 0; i < 4; ++i)
#pragma unroll
        for (int j = 0; j < 4; ++j)
#pragma unroll
            for (int r = 0; r < 4; ++r) acc[i][j][r] = 0.f;

    // staging: wave w stages one array (0:Ah 1:Al 2:Bh 3:Bl), 8 blocks x 1 KB,
    // each gl16 reads a contiguous 1 KB fragment block.
    const ushort_t* gsrc = (w == 0) ? Ah : (w == 1) ? Al : (w == 2) ? Bh : Bl;
    ushort_t* ld0 = (w == 0) ? AshB[0] : (w == 1) ? AslB[0] : (w == 2) ? BshB[0] : BslB[0];
    ushort_t* ld1 = (w == 0) ? AshB[1] : (w == 1) ? AslB[1] : (w == 2) ? BshB[1] : BslB[1];
    const int n16base = ((w < 2) ? row0 : col0) >> 4;

    // prologue: issue k-chunk 0 into buffer 0
#pragma unroll
    for (int mb = 0; mb < 8; ++mb)
        gl16(gsrc + (((size_t)(n16base + mb) * 16 + 0) << 9) + lane * 8,
             ld0 + mb * 512);

#pragma unroll 2
    for (int it = 0; it < 16; ++it) {
        const int cur = it & 1;
        __builtin_amdgcn_s_waitcnt(0x0F70);   // vmcnt(0): cur buffer landed
        __builtin_amdgcn_s_barrier();         // all waves' DMA landed; all waves
                                              // done reading the other buffer
        if (it < 15) {                        // issue next chunk -> other buffer
            ushort_t* nxt = cur ? ld0 : ld1;
#pragma unroll
            for (int mb = 0; mb < 8; ++mb)
                gl16(gsrc + (((size_t)(n16base + mb) * 16 + (it + 1)) << 9) + lane * 8,
                     nxt + mb * 512);
        }
        const ushort_t* cAh = AshB[cur];
        const ushort_t* cAl = AslB[cur];
        const ushort_t* cBh = BshB[cur];
        const ushort_t* cBl = BslB[cur];

        short8 ahf[4], alf[4], bhf[4], blf[4];
#pragma unroll
        for (int i = 0; i < 4; ++i) {
            ahf[i] = *(const short8*)&cAh[((wy * 4 + i) << 9) + (lane << 3)];
            alf[i] = *(const short8*)&cAl[((wy * 4 + i) << 9) + (lane << 3)];
            bhf[i] = *(const short8*)&cBh[((wx * 4 + i) << 9) + (lane << 3)];
            blf[i] = *(const short8*)&cBl[((wx * 4 + i) << 9) + (lane << 3)];
        }
#pragma unroll
        for (int i = 0; i < 4; ++i)
#pragma unroll
            for (int j = 0; j < 4; ++j) {
                acc[i][j] = __builtin_amdgcn_mfma_f32_16x16x32_bf16(ahf[i], bhf[j], acc[i][j], 0, 0, 0);
                acc[i][j] = __builtin_amdgcn_mfma_f32_16x16x32_bf16(ahf[i], blf[j], acc[i][j], 0, 0, 0);
                acc[i][j] = __builtin_amdgcn_mfma_f32_16x16x32_bf16(alf[i], bhf[j], acc[i][j], 0, 0, 0);
            }
    }

    // ---- epilogue: shift-free sumexp (+ top-2) per row over 128 cols ----
    // C/D layout (16x16x32): col = lane&15, row = (lane>>4)*4 + reg.
    float b4[4];
#pragma unroll
    for (int j = 0; j < 4; ++j) b4[j] = bias[col0 + wx * 64 + j * 16 + (lane & 15)];
    const int colbase = col0 + wx * 64 + (lane & 15);

#pragma unroll
    for (int i = 0; i < 4; ++i) {
#pragma unroll
        for (int r = 0; r < 4; ++r) {
            float s = 0.f;
            float m1 = -3e38f, m2 = -3e38f; int c1 = 0x7fffffff, c2 = 0x7fffffff;
#pragma unroll
            for (int j = 0; j < 4; ++j) {
                float v = acc[i][j][r] + b4[j];
                s += __expf(v);
                if (TOP2) t2_insert(m1, c1, m2, c2, v, colbase + j * 16);
            }
            for (int st = 1; st < 16; st <<= 1) {
                s += __shfl_xor(s, st, 64);
                if (TOP2) {
                    float om1 = __shfl_xor(m1, st, 64); int oc1 = __shfl_xor(c1, st, 64);
                    float om2 = __shfl_xor(m2, st, 64); int oc2 = __shfl_xor(c2, st, 64);
                    t2_insert(m1, c1, m2, c2, om1, oc1);
                    t2_insert(m1, c1, m2, c2, om2, oc2);
                }
            }
            if ((lane & 15) == 0) {
                int rowLoc = wy * 64 + i * 16 + (lane >> 4) * 4 + r;
                sc_s[rowLoc][wx] = s;
                if (TOP2) {
                    sc_m1[rowLoc][wx] = m1; sc_c1[rowLoc][wx] = c1;
                    sc_m2[rowLoc][wx] = m2; sc_c2[rowLoc][wx] = c2;
                }
            }
        }
    }
    __syncthreads();
    if (tid < 128) {
        int rowG = row0 + tid;
        pL[(size_t)rowG * NVB + vb] = sc_s[tid][0] + sc_s[tid][1];
        if (TOP2) {
            float m1 = sc_m1[tid][0]; int c1 = sc_c1[tid][0];
            float m2 = sc_m2[tid][0]; int c2 = sc_c2[tid][0];
            t2_insert(m1, c1, m2, c2, sc_m1[tid][1], sc_c1[tid][1]);
            t2_insert(m1, c1, m2, c2, sc_m2[tid][1], sc_c2[tid][1]);
            pM1[(size_t)rowG * NVB + vb] = m1;
            pM2[(size_t)rowG * NVB + vb] = m2;
            pI1[(size_t)rowG * NVB + vb] = c1;
            pI2[(size_t)rowG * NVB + vb] = c2;
        }
    }
}

// ---------------------------------------------------------------------------
// Kernel 3a: combine source partials -> L (denominator only)
// ---------------------------------------------------------------------------
__global__ __launch_bounds__(256) void k_combine_src(
    const float* __restrict__ pL, int nrows, float* __restrict__ L)
{
    int w = threadIdx.x >> 6, ll = threadIdx.x & 63;
    int row = blockIdx.x * 4 + w;
    if (row >= nrows) return;
    const float* p = &pL[(size_t)row * NVB];
    float s = 0.f;
    for (int vb = ll; vb < NVB; vb += 64) s += p[vb];
    for (int st = 1; st < 64; st <<= 1) s += __shfl_xor(s, st, 64);
    if (ll == 0) L[row] = s;
}

// ---------------------------------------------------------------------------
// Kernel 3b: combine target partials -> L + global approx top-2 candidates
// ---------------------------------------------------------------------------
__global__ __launch_bounds__(256) void k_combine_tgt(
    const float* __restrict__ pL,
    const float* __restrict__ pM1, const float* __restrict__ pM2,
    const int* __restrict__ pI1, const int* __restrict__ pI2,
    float* __restrict__ L, int* __restrict__ C0, int* __restrict__ C1)
{
    int w = threadIdx.x >> 6, ll = threadIdx.x & 63;
    int row = blockIdx.x * 4 + w;
    if (row >= 2048) return;
    size_t base = (size_t)row * NVB;
    float s = 0.f;
    float m1 = -3e38f, m2 = -3e38f; int c1 = 0x7fffffff, c2 = 0x7fffffff;
    for (int vb = ll; vb < NVB; vb += 64) {
        s += pL[base + vb];
        t2_insert(m1, c1, m2, c2, pM1[base + vb], pI1[base + vb]);
        t2_insert(m1, c1, m2, c2, pM2[base + vb], pI2[base + vb]);
    }
    for (int st = 1; st < 64; st <<= 1) {
        s += __shfl_xor(s, st, 64);
        float om1 = __shfl_xor(m1, st, 64); int oc1 = __shfl_xor(c1, st, 64);
        float om2 = __shfl_xor(m2, st, 64); int oc2 = __shfl_xor(c2, st, 64);
        t2_insert(m1, c1, m2, c2, om1, oc1);
        t2_insert(m1, c1, m2, c2, om2, oc2);
    }
    if (ll == 0) { L[row] = s; C0[row] = c1; C1[row] = c2; }
}

// ---------------------------------------------------------------------------
// Kernel 4: emission output (exact f32 dot for gathered columns)
// ---------------------------------------------------------------------------
__global__ __launch_bounds__(256) void k_emission(
    const float* __restrict__ ts, const float* __restrict__ W_sv,
    const float* __restrict__ b_sv, const int* __restrict__ sources,
    const float* __restrict__ L, float* __restrict__ out)
{
    __shared__ float wcol[H];
    __shared__ float sbias;
    int b = blockIdx.y, tx = blockIdx.x;
    int tid = threadIdx.x;
    int s = sources[b * 64 + tx];
    wcol[tid]       = W_sv[(size_t)tid * V + s];
    wcol[tid + 256] = W_sv[(size_t)(tid + 256) * V + s];
    if (tid == 0) sbias = b_sv[s];
    __syncthreads();
    int w = tid >> 6, ll = tid & 63;
    for (int r = w; r <= 64; r += 4) {
        int row = (r < 64) ? (b * 64 + r) : 2048;
        const float* a = &ts[(size_t)row * H];
        float sum = 0.f;
#pragma unroll
        for (int j = 0; j < 8; ++j) sum += a[ll * 8 + j] * wcol[ll * 8 + j];
        for (int m2 = 1; m2 < 64; m2 <<= 1) sum += __shfl_xor(sum, m2, 64);
        float prob = __expf(sum + sbias) / L[row];
        if (r < 64) {
            if (ll == 0) out[b * 8192 + r * 64 + tx] = prob;
        } else {
            out[b * 8192 + (64 + ll) * 64 + tx] = prob;
        }
    }
}

// ---------------------------------------------------------------------------
// Kernel 5: target epilogue — exact recompute of token + 2 argmax candidates
// ---------------------------------------------------------------------------
__global__ __launch_bounds__(256) void k_target_final(
    const float* __restrict__ tstate,
    const float* __restrict__ W_tv, const float* __restrict__ b_tv,
    const int* __restrict__ targets, const int* __restrict__ tlen,
    const float* __restrict__ L, const int* __restrict__ C0,
    const int* __restrict__ C1,
    float* __restrict__ out_exp, float* __restrict__ out_log,
    float* __restrict__ out_pred)
{
    int w = threadIdx.x >> 6, ll = threadIdx.x & 63;
    int row = blockIdx.x * 4 + w;
    if (row >= 2048) return;
    int tok = targets[row], a0 = C0[row], a1 = C1[row];
    const float* a = &tstate[(size_t)row * H];
    float s0 = 0.f, s1 = 0.f, s2 = 0.f;
#pragma unroll
    for (int j = 0; j < 8; ++j) {
        int k = ll * 8 + j;
        float av = a[k];
        const float* wr = &W_tv[(size_t)k * V];
        s0 += av * wr[tok]; s1 += av * wr[a0]; s2 += av * wr[a1];
    }
    for (int st = 1; st < 64; st <<= 1) {
        s0 += __shfl_xor(s0, st, 64);
        s1 += __shfl_xor(s1, st, 64);
        s2 += __shfl_xor(s2, st, 64);
    }
    if (ll == 0) {
        float ltok = s0 + b_tv[tok];
        float v0 = s1 + b_tv[a0], v1 = s2 + b_tv[a1];
        int pred = (v1 > v0 || (v1 == v0 && a1 < a0)) ? a1 : a0;
        float Li = L[row];
        int bb = row >> 6, t = row & 63;
        int mask = (t < tlen[bb]) ? 1 : 0;
        float prob = __expf(ltok) / Li;
        out_exp[row]  = mask ? prob : 0.f;
        out_log[row]  = mask ? (ltok - __logf(Li)) : 0.f;
        out_pred[row] = (float)pred;
    }
}

// ---------------------------------------------------------------------------
extern "C" void kernel_launch(void* const* d_in, const int* in_sizes, int n_in,
                              void* d_out, int out_size, void* d_ws, size_t ws_size,
                              hipStream_t stream)
{
    const float* y_hidden = (const float*)d_in[0];
    const float* y_null   = (const float*)d_in[1];
    const float* tstate   = (const float*)d_in[2];
    const float* W_em     = (const float*)d_in[3];
    const float* b_em     = (const float*)d_in[4];
    const float* W_sv     = (const float*)d_in[5];
    const float* b_sv     = (const float*)d_in[6];
    const float* W_tv     = (const float*)d_in[7];
    const float* b_tv     = (const float*)d_in[8];
    const int*   sources  = (const int*)d_in[9];
    const int*   targets  = (const int*)d_in[10];
    const int*   tlen     = (const int*)d_in[11];

    float* out = (float*)d_out;
    float* out_em   = out;
    float* out_exp  = out + 262144;
    float* out_log  = out + 264192;
    float* out_pred = out + 266240;

    // ---- workspace layout (float units) ----
    float* ws = (float*)d_ws;
    size_t off = 0;
    float*    ts    = ws + off; off += (size_t)2176 * H;
    ushort_t* tsPh  = (ushort_t*)(ws + off); off += (size_t)2176 * H / 2;
    ushort_t* tsPl  = (ushort_t*)(ws + off); off += (size_t)2176 * H / 2;
    ushort_t* ttPh  = (ushort_t*)(ws + off); off += (size_t)2048 * H / 2;
    ushort_t* ttPl  = (ushort_t*)(ws + off); off += (size_t)2048 * H / 2;
    ushort_t* Wh    = (ushort_t*)(ws + off); off += (size_t)V * H / 2;   // reused
    ushort_t* Wl    = (ushort_t*)(ws + off); off += (size_t)V * H / 2;
    float* pL0  = ws + off; off += (size_t)2176 * NVB;
    float* pL1  = ws + off; off += (size_t)2048 * NVB;
    float* pM1a = ws + off; off += (size_t)2048 * NVB;
    float* pM1b = ws + off; off += (size_t)2048 * NVB;
    int*   pI1a = (int*)(ws + off); off += (size_t)2048 * NVB;
    int*   pI1b = (int*)(ws + off); off += (size_t)2048 * NVB;
    float* L0   = ws + off; off += 2176;
    float* L1   = ws + off; off += 2048;
    int*   C0   = (int*)(ws + off); off += 2048;
    int*   C1   = (int*)(ws + off); off += 2048;

    // 1) hidden-state transform
    k_emstate<<<dim3(8, 33), 256, 0, stream>>>(y_hidden, y_null, W_em, b_em, ts);

    // 1b) pack A-side operands into fragment-block bf16 hi/lo
    k_packA<<<(136 * 1024) / 256, 256, 0, stream>>>(ts, 2049, 136, tsPh, tsPl);
    k_packA<<<(128 * 1024) / 256, 256, 0, stream>>>(tstate, 2048, 128, ttPh, ttPl);

    // 2a) source side: pack W_sv, GEMM (grid: rb fastest for B L2 locality)
    k_packW<<<(2000 * 1024) / 256, 256, 0, stream>>>(W_sv, Wh, Wl);
    k_gemm<false><<<dim3(17, NVB), 256, 0, stream>>>(
        tsPh, tsPl, Wh, Wl, b_sv, pL0, nullptr, nullptr, nullptr, nullptr);

    // 2b) target side: pack W_tv (buffer reuse, stream-ordered), GEMM
    k_packW<<<(2000 * 1024) / 256, 256, 0, stream>>>(W_tv, Wh, Wl);
    k_gemm<true><<<dim3(16, NVB), 256, 0, stream>>>(
        ttPh, ttPl, Wh, Wl, b_tv, pL1, pM1a, pM1b, pI1a, pI1b);

    // 3) combine partials
    k_combine_src<<<(2049 + 3) / 4, 256, 0, stream>>>(pL0, 2049, L0);
    k_combine_tgt<<<2048 / 4, 256, 0, stream>>>(pL1, pM1a, pM1b, pI1a, pI1b,
                                                L1, C0, C1);

    // 4) emission gather (exact f32 logits)
    k_emission<<<dim3(64, 32), 256, 0, stream>>>(ts, W_sv, b_sv, sources, L0, out_em);

    // 5) target epilogue with exact candidate recompute
    k_target_final<<<2048 / 4, 256, 0, stream>>>(tstate, W_tv, b_tv, targets, tlen,
                                                 L1, C0, C1,
                                                 out_exp, out_log, out_pred);
}